// Round 9
// baseline (1794.576 us; speedup 1.0000x reference)
//
#include <hip/hip_runtime.h>

typedef unsigned short ushort_t;
typedef unsigned int uint_t;
typedef unsigned long long ull_t;
typedef short v8s __attribute__((ext_vector_type(8)));
typedef float v4f __attribute__((ext_vector_type(4)));

__device__ __forceinline__ float b2f(ushort_t u) {
    uint_t x = ((uint_t)u) << 16;
    float f;
    __builtin_memcpy(&f, &x, 4);
    return f;
}
__device__ __forceinline__ ushort_t f2b(float f) {
    uint_t x;
    __builtin_memcpy(&x, &f, 4);
    uint_t r = (x + 0x7FFFu + ((x >> 16) & 1u)) >> 16;
    return (ushort_t)r;
}

// ---------------------------------------------------------------------------
// k_setup: zero 8-slot h ring (64 blocks) + weight fp32->bf16 conversions.
// ---------------------------------------------------------------------------
__global__ __launch_bounds__(256) void k_setup(
    const float* __restrict__ Wih, const float* __restrict__ Whh,
    const float* __restrict__ Wgh, const float* __restrict__ Whist,
    const float* __restrict__ Wfeat,
    ushort_t* __restrict__ Wih_b, ushort_t* __restrict__ Whh_b,
    ushort_t* __restrict__ Wgh_b, ushort_t* __restrict__ Whist_b,
    ushort_t* __restrict__ Wfeat_b, ull_t* __restrict__ hbufs) {
    int bid = blockIdx.x, tid = threadIdx.x;
    if (bid < 64) {   // zero 8 slots x 131072 u16 = 262144 ull
        ull_t* p = hbufs + (size_t)bid * 4096 + tid;
#pragma unroll
        for (int i = 0; i < 16; ++i) p[i * 256] = 0;
        return;
    }
    bid -= 64;
    const float* src; ushort_t* dst; int n;
    if (bid < 1024)      { src = Wih;   dst = Wih_b;   n = 262144; }
    else if (bid < 5120) { bid -= 1024; src = Whh;   dst = Whh_b;   n = 1048576; }
    else if (bid < 5248) { bid -= 5120; src = Wgh;   dst = Wgh_b;   n = 32768; }
    else if (bid < 5376) { bid -= 5248; src = Whist; dst = Whist_b; n = 32768; }
    else                 { bid -= 5376; src = Wfeat; dst = Wfeat_b; n = 4096; }
    int i = bid * 256 + tid;
    if (i < n) dst[i] = f2b(src[i]);
}

// ---------------------------------------------------------------------------
// k_pre: 512 blocks; each block = 32 (b,c) pairs x 8 threads over T chunks.
// ---------------------------------------------------------------------------
__global__ __launch_bounds__(256) void k_pre(
    const float* __restrict__ data, const float* __restrict__ Wgx,
    const float* __restrict__ bgx,
    ushort_t* __restrict__ values, ushort_t* __restrict__ masks,
    ushort_t* __restrict__ deltas, ushort_t* __restrict__ gammax) {
    __shared__ int lastl[32][9];
    int tid = threadIdx.x;
    int j = tid >> 5, p = tid & 31;
    int pid = blockIdx.x * 32 + p;      // 0..16383
    int b = pid >> 6, c = pid & 63;
    float wd = Wgx[c * 64 + c], bg = bgx[c];
    int t0 = j * 32;
    const float* dp = data + (size_t)b * 16384 + c;
    float v[32]; uint_t bits = 0;
#pragma unroll
    for (int s = 0; s < 32; ++s) {
        float x = dp[(t0 + s) * 64];
        bool obs = (x == x);
        v[s] = obs ? x : 0.f;
        bits |= obs ? (1u << s) : 0u;
    }
    uint_t vb = bits;
    if (j == 0) vb &= ~1u;              // t=0 never counts as observation
    int lastloc = 0;
    if (vb) lastloc = t0 + (31 - __clz(vb));
    lastl[p][j] = lastloc;
    __syncthreads();
    int L = 0;
    for (int jj = 0; jj < j; ++jj) L = max(L, lastl[p][jj]);
#pragma unroll
    for (int s = 0; s < 32; ++s) {
        int t = t0 + s;
        float m = ((bits >> s) & 1) ? 1.f : 0.f;
        float d = (t == 0) ? 0.f : (float)(t - L);
        float sg = d * wd + bg;
        float gx = (sg > 0.f) ? __expf(-sg) : 1.f;
        size_t o = (size_t)t * 16384 + pid;
        values[o] = f2b(v[s]); masks[o] = f2b(m);
        deltas[o] = f2b(d);    gammax[o] = f2b(gx);
        if (((bits >> s) & 1) && t >= 1) L = t;
    }
}

// ---------------------------------------------------------------------------
// k_alpha: 4096 blocks x 16 (t,b) rows (T*B = 65536 rows).
// ---------------------------------------------------------------------------
__global__ __launch_bounds__(256) void k_alpha(
    const ushort_t* __restrict__ gammax, const ushort_t* __restrict__ masks,
    const float* __restrict__ Wcomb, const float* __restrict__ bcomb,
    ushort_t* __restrict__ alpha) {
    __shared__ __attribute__((aligned(16))) ushort_t wl[64 * 136];
    __shared__ __attribute__((aligned(16))) ushort_t al[16 * 136];
    int tid = threadIdx.x;
    for (int idx = tid; idx < 8192; idx += 256) {
        int r = idx >> 7, kcol = idx & 127;
        wl[r * 136 + kcol] = f2b(Wcomb[idx]);
    }
    int tb0 = blockIdx.x * 16;
    for (int idx = tid; idx < 2048; idx += 256) {
        int r = idx >> 7, kcol = idx & 127;
        al[r * 136 + kcol] = (kcol < 64)
            ? gammax[(size_t)(tb0 + r) * 64 + kcol]
            : masks[(size_t)(tb0 + r) * 64 + (kcol - 64)];
    }
    __syncthreads();
    int i = tid & 63, rg = (tid >> 6) * 4;
    float bc = bcomb[i];
    float acc[4] = {bc, bc, bc, bc};
#pragma unroll
    for (int k8 = 0; k8 < 16; ++k8) {
        v8s w8 = *(const v8s*)(wl + i * 136 + k8 * 8);
#pragma unroll
        for (int rr = 0; rr < 4; ++rr) {
            v8s a8 = *(const v8s*)(al + (rg + rr) * 136 + k8 * 8);
#pragma unroll
            for (int q = 0; q < 8; ++q)
                acc[rr] += b2f((ushort_t)a8[q]) * b2f((ushort_t)w8[q]);
        }
    }
#pragma unroll
    for (int rr = 0; rr < 4; ++rr)
        alpha[(size_t)(tb0 + rg + rr) * 64 + i] = f2b(acc[rr]);
}

// ---------------------------------------------------------------------------
// k_run: persistent, 128 wgs = 8 batch-pairs x 16 col-blocks.  Each wg runs
// TWO interleaved recurrences (batch rows [32p,32p+16) and [32p+16,32p+32)):
// group A's h store -> h poll gap contains group B's whole phase, hiding the
// cross-wg exchange latency + straggler skew.  LDS buffers shared between
// phases (strictly sequential); weights identical for both groups.
// 8-slot h ring + data-polling (bf16+1) + producer pre-zero of slot (t+4)%8.
// ---------------------------------------------------------------------------
__global__ __launch_bounds__(256, 1) void k_run(
    const ushort_t* __restrict__ values, const ushort_t* __restrict__ masks,
    const ushort_t* __restrict__ deltas, const ushort_t* __restrict__ alpha,
    const ushort_t* __restrict__ Wih, const ushort_t* __restrict__ Whh,
    const float* __restrict__ bih, const float* __restrict__ bhh,
    const ushort_t* __restrict__ Wgh, const float* __restrict__ bgh,
    const ushort_t* __restrict__ Whist, const float* __restrict__ bhist,
    const ushort_t* __restrict__ Wfeat, const float* __restrict__ bfeat,
    ushort_t* __restrict__ hbufs, float* __restrict__ out) {
    __shared__ __attribute__((aligned(16))) ushort_t hlds[16 * 520];
    __shared__ __attribute__((aligned(16))) ushort_t inplds[16 * 136];
    __shared__ __attribute__((aligned(16))) ushort_t xclds[16 * 72];
    __shared__ __attribute__((aligned(16))) ushort_t d1b[16 * 72];
    __shared__ __attribute__((aligned(16))) float gl[4 * 16 * 36];
    __shared__ __attribute__((aligned(16))) float gam[16 * 36];

    int tid = threadIdx.x;
    int w = tid >> 6;
    int lane = tid & 63;
    int l15 = lane & 15, quad = lane >> 4;
    int wg = blockIdx.x;
    int pr = wg & 7, cb = wg >> 3;      // pair 0..7, col-block 0..15
    int b0g[2] = {pr * 32, pr * 32 + 16};

    // ---- persistent weight fragments (shared by both groups) ----
    v8s whhF[2][16], wihF[2][4], whisF[16], wfF[2], wghF[2] = {};
    float biasv[2];
#pragma unroll
    for (int nt2 = 0; nt2 < 2; ++nt2) {
        int hc = cb * 32 + nt2 * 16 + l15;
        int rW = w * 512 + hc;
        const ushort_t* whrow = Whh + (size_t)rW * 512;
        const ushort_t* wirow = Wih + (size_t)rW * 128;
#pragma unroll
        for (int kt = 0; kt < 16; ++kt)
            whhF[nt2][kt] = *(const v8s*)(whrow + kt * 32 + quad * 8);
#pragma unroll
        for (int kt = 0; kt < 4; ++kt)
            wihF[nt2][kt] = *(const v8s*)(wirow + kt * 32 + quad * 8);
        biasv[nt2] = bih[rW] + bhh[rW];
    }
    int colC = w * 16 + l15;
    {
        const ushort_t* hrow = Whist + (size_t)colC * 512;
#pragma unroll
        for (int kt = 0; kt < 16; ++kt)
            whisF[kt] = *(const v8s*)(hrow + kt * 32 + quad * 8);
        const ushort_t* frow = Wfeat + colC * 64;
#pragma unroll
        for (int kt = 0; kt < 2; ++kt) {
            int k0 = kt * 32 + quad * 8;
            v8s bb = *(const v8s*)(frow + k0);
#pragma unroll
            for (int j = 0; j < 8; ++j)
                if (k0 + j == colC) bb[j] = 0;   // zero diagonal
            wfF[kt] = bb;
        }
    }
    float bghv = 0.f;
    if (w < 2) {
        int gcol = cb * 32 + w * 16 + l15;
        const ushort_t* grow = Wgh + gcol * 64;
#pragma unroll
        for (int kt = 0; kt < 2; ++kt)
            wghF[kt] = *(const v8s*)(grow + kt * 32 + quad * 8);
        bghv = bgh[gcol];
    }
    float bhistv = bhist[colC];
    float bfeatv = bfeat[colC];

    int sf_row = tid >> 3, sf_c4 = (tid & 7) * 4;
    float c_reg4[2][4] = {{0.f, 0.f, 0.f, 0.f}, {0.f, 0.f, 0.f, 0.f}};

    for (int t = 0; t < 256; ++t) {
        for (int g = 0; g < 2; ++g) {
            int b0 = b0g[g];

            // ---- P: prefetch (no cross-wg deps) ----
            float v4r[4], m4r[4], a4r[4];
#pragma unroll
            for (int r = 0; r < 4; ++r) {
                int row = quad * 4 + r;
                size_t gi = (size_t)t * 16384 + (b0 + row) * 64 + colC;
                v4r[r] = b2f(values[gi]);
                m4r[r] = b2f(masks[gi]);
                a4r[r] = b2f(alpha[gi]);
            }
            v8s mreg = {}, dreg = {};
            if (tid < 128) {
                int row = tid >> 3, c8 = (tid & 7) * 8;
                int tn = (t < 255) ? t + 1 : 255;
                mreg = *(const v8s*)(masks + (size_t)t * 16384 + (b0 + row) * 64 + c8);
                dreg = *(const v8s*)(deltas + (size_t)tn * 16384 + (b0 + row) * 64 + c8);
            }

            // ---- S0: poll h(t) data directly; decode; stage LDS ----
            if (t == 0) {
                v8s z = {0, 0, 0, 0, 0, 0, 0, 0};
                for (int idx = tid; idx < 1040; idx += 256) ((v8s*)hlds)[idx] = z;
            } else {
                const ushort_t* hb = hbufs + (size_t)(t & 7) * 131072;
                const ull_t* hp[8];
                ull_t hv[8];
#pragma unroll
                for (int i = 0; i < 8; ++i) {
                    int c = tid + 256 * i;
                    int row = c >> 7, c4 = (c & 127) * 4;
                    hp[i] = (const ull_t*)(hb + (b0 + row) * 512 + c4);
                    hv[i] = __hip_atomic_load(hp[i], __ATOMIC_RELAXED,
                                              __HIP_MEMORY_SCOPE_AGENT);
                }
                int guard = 0;
                while (true) {
                    bool any = false;
#pragma unroll
                    for (int i = 0; i < 8; ++i) any |= (hv[i] == 0);
                    if (!any || ++guard > (1 << 20)) break;
                    __builtin_amdgcn_s_sleep(1);
#pragma unroll
                    for (int i = 0; i < 8; ++i)
                        if (hv[i] == 0)
                            hv[i] = __hip_atomic_load(hp[i], __ATOMIC_RELAXED,
                                                      __HIP_MEMORY_SCOPE_AGENT);
                }
#pragma unroll
                for (int i = 0; i < 8; ++i) {
                    int c = tid + 256 * i;
                    int row = c >> 7, c4 = (c & 127) * 4;
                    *(ull_t*)(hlds + row * 520 + c4) =
                        hv[i] - 0x0001000100010001ULL;   // decode bf16+1
                }
            }
            if (tid < 128) {
                int row = tid >> 3, c8 = (tid & 7) * 8;
                *(v8s*)(inplds + row * 136 + 64 + c8) = mreg;
                *(v8s*)(d1b + row * 72 + c8) = dreg;
            }
            __syncthreads();

            // ---- SA: xh + 2 gate chains share A-frags; gamma; xc epilogue --
            v4f accx = {0.f, 0.f, 0.f, 0.f};
            v4f accg0 = {0.f, 0.f, 0.f, 0.f}, accg1 = {0.f, 0.f, 0.f, 0.f};
#pragma unroll
            for (int kt = 0; kt < 16; ++kt) {
                v8s a = *(const v8s*)(hlds + l15 * 520 + kt * 32 + quad * 8);
                accx = __builtin_amdgcn_mfma_f32_16x16x32_bf16(a, whisF[kt], accx, 0, 0, 0);
                accg0 = __builtin_amdgcn_mfma_f32_16x16x32_bf16(a, whhF[0][kt], accg0, 0, 0, 0);
                accg1 = __builtin_amdgcn_mfma_f32_16x16x32_bf16(a, whhF[1][kt], accg1, 0, 0, 0);
            }
            if (w < 2) {
                v4f acc = {0.f, 0.f, 0.f, 0.f};
#pragma unroll
                for (int kt = 0; kt < 2; ++kt) {
                    v8s a = *(const v8s*)(d1b + l15 * 72 + kt * 32 + quad * 8);
                    acc = __builtin_amdgcn_mfma_f32_16x16x32_bf16(a, wghF[kt], acc, 0, 0, 0);
                }
#pragma unroll
                for (int r = 0; r < 4; ++r) {
                    float s = acc[r] + bghv;
                    gam[(quad * 4 + r) * 36 + w * 16 + l15] = (s > 0.f) ? __expf(-s) : 1.f;
                }
            }
            float xh4[4];
#pragma unroll
            for (int r = 0; r < 4; ++r) {
                float xh = accx[r] + bhistv;
                float xc = m4r[r] * v4r[r] + (1.f - m4r[r]) * xh;
                xclds[(quad * 4 + r) * 72 + colC] = f2b(xc);
                xh4[r] = xh;
            }
            __syncthreads();

            // ---- SC: z_h MFMA; c_h/c_c epilogue; out store ----
            {
                v4f accz = {0.f, 0.f, 0.f, 0.f};
#pragma unroll
                for (int kt = 0; kt < 2; ++kt) {
                    v8s a = *(const v8s*)(xclds + l15 * 72 + kt * 32 + quad * 8);
                    accz = __builtin_amdgcn_mfma_f32_16x16x32_bf16(a, wfF[kt], accz, 0, 0, 0);
                }
#pragma unroll
                for (int r = 0; r < 4; ++r) {
                    float zh = accz[r] + bfeatv;
                    float ch = a4r[r] * zh + (1.f - a4r[r]) * xh4[r];
                    float cc = m4r[r] * v4r[r] + (1.f - m4r[r]) * ch;
                    int row = quad * 4 + r;
                    inplds[row * 136 + colC] = f2b(cc);
                    if (cb == 0)
                        out[(size_t)(b0 + row) * 16384 + t * 64 + colC] = cc;
                }
            }
            __syncthreads();

            // ---- SE: gates Wih part; gate planes ----
#pragma unroll
            for (int nt2 = 0; nt2 < 2; ++nt2) {
                v4f acc = (nt2 == 0) ? accg0 : accg1;
#pragma unroll
                for (int kt = 0; kt < 4; ++kt) {
                    v8s a = *(const v8s*)(inplds + l15 * 136 + kt * 32 + quad * 8);
                    acc = __builtin_amdgcn_mfma_f32_16x16x32_bf16(a, wihF[nt2][kt], acc, 0, 0, 0);
                }
#pragma unroll
                for (int r = 0; r < 4; ++r)
                    gl[w * 576 + (quad * 4 + r) * 36 + nt2 * 16 + l15] = acc[r] + biasv[nt2];
            }
            __syncthreads();

            // ---- SF: LSTM + decay + encoded h store; pre-zero slot t+4 ----
            if (tid < 128) {
                ull_t outv = 0;
#pragma unroll
                for (int j = 0; j < 4; ++j) {
                    int hcl = sf_c4 + j;
                    float gi = gl[0 * 576 + sf_row * 36 + hcl];
                    float gf = gl[1 * 576 + sf_row * 36 + hcl];
                    float gg = gl[2 * 576 + sf_row * 36 + hcl];
                    float go = gl[3 * 576 + sf_row * 36 + hcl];
                    float si = 1.f / (1.f + __expf(-gi));
                    float sf = 1.f / (1.f + __expf(-gf));
                    float tg = 1.f - 2.f / (__expf(2.f * gg) + 1.f);
                    float so = 1.f / (1.f + __expf(-go));
                    float cn = sf * c_reg4[g][j] + si * tg;
                    c_reg4[g][j] = cn;
                    float hn = so * (1.f - 2.f / (__expf(2.f * cn) + 1.f));
                    float gm = gam[sf_row * 36 + hcl];
                    outv |= (ull_t)(ushort_t)(f2b(hn * gm) + 1) << (16 * j);
                }
                size_t myoff = (size_t)(b0 + sf_row) * 512 + cb * 32 + sf_c4;
                if (t < 255) {
                    ushort_t* hnx = hbufs + (size_t)((t + 1) & 7) * 131072;
                    __hip_atomic_store((ull_t*)(hnx + myoff), outv,
                                       __ATOMIC_RELAXED, __HIP_MEMORY_SCOPE_AGENT);
                }
                if (t + 4 < 256) {
                    ushort_t* hz = hbufs + (size_t)((t + 4) & 7) * 131072;
                    __hip_atomic_store((ull_t*)(hz + myoff), 0ULL,
                                       __ATOMIC_RELAXED, __HIP_MEMORY_SCOPE_AGENT);
                }
            }
            __syncthreads();   // drains vmcnt: LDS reuse + publishes stores
        }
    }
}

extern "C" void kernel_launch(void* const* d_in, const int* in_sizes, int n_in,
                              void* d_out, int out_size, void* d_ws, size_t ws_size,
                              hipStream_t stream) {
    const float* data  = (const float*)d_in[0];
    const float* Wih   = (const float*)d_in[1];
    const float* Whh   = (const float*)d_in[2];
    const float* bih   = (const float*)d_in[3];
    const float* bhh   = (const float*)d_in[4];
    const float* Wgh   = (const float*)d_in[5];
    const float* bgh   = (const float*)d_in[6];
    const float* Wgx   = (const float*)d_in[7];
    const float* bgx   = (const float*)d_in[8];
    const float* Whist = (const float*)d_in[9];
    const float* bhist = (const float*)d_in[10];
    const float* Wfeat = (const float*)d_in[11];
    const float* bfeat = (const float*)d_in[12];
    const float* Wcomb = (const float*)d_in[13];
    const float* bcomb = (const float*)d_in[14];
    float* out = (float*)d_out;

    char* ws = (char*)d_ws;
    const size_t NTBC = 256UL * 256 * 64;
    ushort_t* valuesb = (ushort_t*)ws; ws += NTBC * 2;
    ushort_t* masksp  = (ushort_t*)ws; ws += NTBC * 2;
    ushort_t* deltasp = (ushort_t*)ws; ws += NTBC * 2;
    ushort_t* gammax  = (ushort_t*)ws; ws += NTBC * 2;
    ushort_t* alphap  = (ushort_t*)ws; ws += NTBC * 2;
    ushort_t* Wih_b   = (ushort_t*)ws; ws += 2048UL * 128 * 2;
    ushort_t* Whh_b   = (ushort_t*)ws; ws += 2048UL * 512 * 2;
    ushort_t* Wgh_b   = (ushort_t*)ws; ws += 512UL * 64 * 2;
    ushort_t* Whist_b = (ushort_t*)ws; ws += 64UL * 512 * 2;
    ushort_t* Wfeat_b = (ushort_t*)ws; ws += 64UL * 64 * 2;
    ushort_t* hbufs   = (ushort_t*)ws; ws += 8UL * 131072 * 2;  // 2 MB ring
    // total ~44.6 MiB

    k_setup<<<5456, 256, 0, stream>>>(Wih, Whh, Wgh, Whist, Wfeat,
                                      Wih_b, Whh_b, Wgh_b, Whist_b, Wfeat_b,
                                      (ull_t*)hbufs);
    k_pre<<<512, 256, 0, stream>>>(data, Wgx, bgx, valuesb, masksp, deltasp, gammax);
    k_alpha<<<4096, 256, 0, stream>>>(gammax, masksp, Wcomb, bcomb, alphap);
    k_run<<<128, 256, 0, stream>>>(valuesb, masksp, deltasp, alphap,
                                   Wih_b, Whh_b, bih, bhh,
                                   Wgh_b, bgh, Whist_b, bhist,
                                   Wfeat_b, bfeat, hbufs, out);
}

// Round 10
// 1499.754 us; speedup vs baseline: 1.1966x; 1.1966x over previous
//
#include <hip/hip_runtime.h>

typedef unsigned short ushort_t;
typedef unsigned int uint_t;
typedef unsigned long long ull_t;
typedef short v8s __attribute__((ext_vector_type(8)));
typedef float v4f __attribute__((ext_vector_type(4)));

__device__ __forceinline__ float b2f(ushort_t u) {
    uint_t x = ((uint_t)u) << 16;
    float f;
    __builtin_memcpy(&f, &x, 4);
    return f;
}
__device__ __forceinline__ ushort_t f2b(float f) {
    uint_t x;
    __builtin_memcpy(&x, &f, 4);
    uint_t r = (x + 0x7FFFu + ((x >> 16) & 1u)) >> 16;
    return (ushort_t)r;
}

// ---------------------------------------------------------------------------
// k_setup: zero BOTH h rings (128 blocks) + weight fp32->bf16 conversions.
// grid = 128 + 1024 + 4096 + 128 + 128 + 16 = 5520 blocks of 256.
// ---------------------------------------------------------------------------
__global__ __launch_bounds__(256) void k_setup(
    const float* __restrict__ Wih, const float* __restrict__ Whh,
    const float* __restrict__ Wgh, const float* __restrict__ Whist,
    const float* __restrict__ Wfeat,
    ushort_t* __restrict__ Wih_b, ushort_t* __restrict__ Whh_b,
    ushort_t* __restrict__ Wgh_b, ushort_t* __restrict__ Whist_b,
    ushort_t* __restrict__ Wfeat_b, ull_t* __restrict__ rings) {
    int bid = blockIdx.x, tid = threadIdx.x;
    if (bid < 128) {   // zero 2 rings x 8 slots x 131072 u16 = 524288 ull
        ull_t* p = rings + (size_t)bid * 4096 + tid;
#pragma unroll
        for (int i = 0; i < 16; ++i) p[i * 256] = 0;
        return;
    }
    bid -= 128;
    const float* src; ushort_t* dst; int n;
    if (bid < 1024)      { src = Wih;   dst = Wih_b;   n = 262144; }
    else if (bid < 5120) { bid -= 1024; src = Whh;   dst = Whh_b;   n = 1048576; }
    else if (bid < 5248) { bid -= 5120; src = Wgh;   dst = Wgh_b;   n = 32768; }
    else if (bid < 5376) { bid -= 5248; src = Whist; dst = Whist_b; n = 32768; }
    else                 { bid -= 5376; src = Wfeat; dst = Wfeat_b; n = 4096; }
    int i = bid * 256 + tid;
    if (i < n) dst[i] = f2b(src[i]);
}

// ---------------------------------------------------------------------------
// k_pre: 512 blocks; each block = 32 (b,c) pairs x 8 threads over T chunks.
// ---------------------------------------------------------------------------
__global__ __launch_bounds__(256) void k_pre(
    const float* __restrict__ data, const float* __restrict__ Wgx,
    const float* __restrict__ bgx,
    ushort_t* __restrict__ values, ushort_t* __restrict__ masks,
    ushort_t* __restrict__ deltas, ushort_t* __restrict__ gammax) {
    __shared__ int lastl[32][9];
    int tid = threadIdx.x;
    int j = tid >> 5, p = tid & 31;
    int pid = blockIdx.x * 32 + p;      // 0..16383
    int b = pid >> 6, c = pid & 63;
    float wd = Wgx[c * 64 + c], bg = bgx[c];
    int t0 = j * 32;
    const float* dp = data + (size_t)b * 16384 + c;
    float v[32]; uint_t bits = 0;
#pragma unroll
    for (int s = 0; s < 32; ++s) {
        float x = dp[(t0 + s) * 64];
        bool obs = (x == x);
        v[s] = obs ? x : 0.f;
        bits |= obs ? (1u << s) : 0u;
    }
    uint_t vb = bits;
    if (j == 0) vb &= ~1u;              // t=0 never counts as observation
    int lastloc = 0;
    if (vb) lastloc = t0 + (31 - __clz(vb));
    lastl[p][j] = lastloc;
    __syncthreads();
    int L = 0;
    for (int jj = 0; jj < j; ++jj) L = max(L, lastl[p][jj]);
#pragma unroll
    for (int s = 0; s < 32; ++s) {
        int t = t0 + s;
        float m = ((bits >> s) & 1) ? 1.f : 0.f;
        float d = (t == 0) ? 0.f : (float)(t - L);
        float sg = d * wd + bg;
        float gx = (sg > 0.f) ? __expf(-sg) : 1.f;
        size_t o = (size_t)t * 16384 + pid;
        values[o] = f2b(v[s]); masks[o] = f2b(m);
        deltas[o] = f2b(d);    gammax[o] = f2b(gx);
        if (((bits >> s) & 1) && t >= 1) L = t;
    }
}

// ---------------------------------------------------------------------------
// k_alpha: 4096 blocks x 16 (t,b) rows (T*B = 65536 rows).
// ---------------------------------------------------------------------------
__global__ __launch_bounds__(256) void k_alpha(
    const ushort_t* __restrict__ gammax, const ushort_t* __restrict__ masks,
    const float* __restrict__ Wcomb, const float* __restrict__ bcomb,
    ushort_t* __restrict__ alpha) {
    __shared__ __attribute__((aligned(16))) ushort_t wl[64 * 136];
    __shared__ __attribute__((aligned(16))) ushort_t al[16 * 136];
    int tid = threadIdx.x;
    for (int idx = tid; idx < 8192; idx += 256) {
        int r = idx >> 7, kcol = idx & 127;
        wl[r * 136 + kcol] = f2b(Wcomb[idx]);
    }
    int tb0 = blockIdx.x * 16;
    for (int idx = tid; idx < 2048; idx += 256) {
        int r = idx >> 7, kcol = idx & 127;
        al[r * 136 + kcol] = (kcol < 64)
            ? gammax[(size_t)(tb0 + r) * 64 + kcol]
            : masks[(size_t)(tb0 + r) * 64 + (kcol - 64)];
    }
    __syncthreads();
    int i = tid & 63, rg = (tid >> 6) * 4;
    float bc = bcomb[i];
    float acc[4] = {bc, bc, bc, bc};
#pragma unroll
    for (int k8 = 0; k8 < 16; ++k8) {
        v8s w8 = *(const v8s*)(wl + i * 136 + k8 * 8);
#pragma unroll
        for (int rr = 0; rr < 4; ++rr) {
            v8s a8 = *(const v8s*)(al + (rg + rr) * 136 + k8 * 8);
#pragma unroll
            for (int q = 0; q < 8; ++q)
                acc[rr] += b2f((ushort_t)a8[q]) * b2f((ushort_t)w8[q]);
        }
    }
#pragma unroll
    for (int rr = 0; rr < 4; ++rr)
        alpha[(size_t)(tb0 + rg + rr) * 64 + i] = f2b(acc[rr]);
}

// ---------------------------------------------------------------------------
// k_run: R8 structure (256 wgs = 16 batch-groups x 16 col-blocks, weights in
// VGPRs, 8-slot ring, data-polling bf16+1, pre-zero slot (t+4)%8) with a
// DUAL-PATH h exchange:
//   fast: volatile store/load -> same-XCD L2 (group {rb, rb+16,..} all map to
//         XCD rb%8 under round-robin; ~200-300 cyc RTT)
//   slow: relaxed agent atomics -> L3 (R8's path; polled every 4th spin)
// Correct regardless of the blockIdx->XCD mapping: if fast never becomes
// visible, the slow path completes the poll (degenerates to R8).
// ---------------------------------------------------------------------------
__global__ __launch_bounds__(256, 1) void k_run(
    const ushort_t* __restrict__ values, const ushort_t* __restrict__ masks,
    const ushort_t* __restrict__ deltas, const ushort_t* __restrict__ alpha,
    const ushort_t* __restrict__ Wih, const ushort_t* __restrict__ Whh,
    const float* __restrict__ bih, const float* __restrict__ bhh,
    const ushort_t* __restrict__ Wgh, const float* __restrict__ bgh,
    const ushort_t* __restrict__ Whist, const float* __restrict__ bhist,
    const ushort_t* __restrict__ Wfeat, const float* __restrict__ bfeat,
    ushort_t* __restrict__ hfast, ushort_t* __restrict__ hslow,
    float* __restrict__ out) {
    __shared__ __attribute__((aligned(16))) ushort_t hlds[16 * 520];
    __shared__ __attribute__((aligned(16))) ushort_t inplds[16 * 136];
    __shared__ __attribute__((aligned(16))) ushort_t xclds[16 * 72];
    __shared__ __attribute__((aligned(16))) ushort_t d1b[16 * 72];
    __shared__ __attribute__((aligned(16))) float gl[4 * 16 * 36];
    __shared__ __attribute__((aligned(16))) float gam[16 * 36];

    int tid = threadIdx.x;
    int w = tid >> 6;
    int lane = tid & 63;
    int l15 = lane & 15, quad = lane >> 4;
    int wg = blockIdx.x;
    int rb = wg & 15, cb = wg >> 4;
    int b0 = rb * 16;

    // ---- persistent weight fragments ----
    v8s whhF[2][16], wihF[2][4], whisF[16], wfF[2], wghF[2] = {};
    float biasv[2];
#pragma unroll
    for (int nt2 = 0; nt2 < 2; ++nt2) {
        int hc = cb * 32 + nt2 * 16 + l15;
        int rW = w * 512 + hc;
        const ushort_t* whrow = Whh + (size_t)rW * 512;
        const ushort_t* wirow = Wih + (size_t)rW * 128;
#pragma unroll
        for (int kt = 0; kt < 16; ++kt)
            whhF[nt2][kt] = *(const v8s*)(whrow + kt * 32 + quad * 8);
#pragma unroll
        for (int kt = 0; kt < 4; ++kt)
            wihF[nt2][kt] = *(const v8s*)(wirow + kt * 32 + quad * 8);
        biasv[nt2] = bih[rW] + bhh[rW];
    }
    int colC = w * 16 + l15;
    {
        const ushort_t* hrow = Whist + (size_t)colC * 512;
#pragma unroll
        for (int kt = 0; kt < 16; ++kt)
            whisF[kt] = *(const v8s*)(hrow + kt * 32 + quad * 8);
        const ushort_t* frow = Wfeat + colC * 64;
#pragma unroll
        for (int kt = 0; kt < 2; ++kt) {
            int k0 = kt * 32 + quad * 8;
            v8s bb = *(const v8s*)(frow + k0);
#pragma unroll
            for (int j = 0; j < 8; ++j)
                if (k0 + j == colC) bb[j] = 0;   // zero diagonal
            wfF[kt] = bb;
        }
    }
    float bghv = 0.f;
    if (w < 2) {
        int gcol = cb * 32 + w * 16 + l15;
        const ushort_t* grow = Wgh + gcol * 64;
#pragma unroll
        for (int kt = 0; kt < 2; ++kt)
            wghF[kt] = *(const v8s*)(grow + kt * 32 + quad * 8);
        bghv = bgh[gcol];
    }
    float bhistv = bhist[colC];
    float bfeatv = bfeat[colC];

    int sf_row = tid >> 3, sf_c4 = (tid & 7) * 4;
    float c_reg4[4] = {0.f, 0.f, 0.f, 0.f};

    for (int t = 0; t < 256; ++t) {
        // ---- P: prefetch (no cross-wg deps) ----
        float v4r[4], m4r[4], a4r[4];
#pragma unroll
        for (int r = 0; r < 4; ++r) {
            int row = quad * 4 + r;
            size_t g = (size_t)t * 16384 + (b0 + row) * 64 + colC;
            v4r[r] = b2f(values[g]);
            m4r[r] = b2f(masks[g]);
            a4r[r] = b2f(alpha[g]);
        }
        v8s mreg = {}, dreg = {};
        if (tid < 128) {
            int row = tid >> 3, c8 = (tid & 7) * 8;
            int tn = (t < 255) ? t + 1 : 255;
            mreg = *(const v8s*)(masks + (size_t)t * 16384 + (b0 + row) * 64 + c8);
            dreg = *(const v8s*)(deltas + (size_t)tn * 16384 + (b0 + row) * 64 + c8);
        }

        // ---- S0: dual-path poll of h(t); decode; stage LDS ----
        if (t == 0) {
            v8s z = {0, 0, 0, 0, 0, 0, 0, 0};
            for (int idx = tid; idx < 1040; idx += 256) ((v8s*)hlds)[idx] = z;
        } else {
            const ushort_t* hf = hfast + (size_t)(t & 7) * 131072;
            const ushort_t* hs = hslow + (size_t)(t & 7) * 131072;
            const ull_t* fp[8];
            const ull_t* sp[8];
            ull_t hv[8];
#pragma unroll
            for (int i = 0; i < 8; ++i) {
                int c = tid + 256 * i;
                int row = c >> 7, c4 = (c & 127) * 4;
                size_t off = (size_t)(b0 + row) * 512 + c4;
                fp[i] = (const ull_t*)(hf + off);
                sp[i] = (const ull_t*)(hs + off);
                hv[i] = *(volatile const ull_t*)fp[i];
            }
            int guard = 0;
            while (true) {
                bool any = false;
#pragma unroll
                for (int i = 0; i < 8; ++i) any |= (hv[i] == 0);
                if (!any || ++guard > (1 << 20)) break;
                __builtin_amdgcn_s_sleep(1);
                bool slow = ((guard & 3) == 3);
#pragma unroll
                for (int i = 0; i < 8; ++i)
                    if (hv[i] == 0)
                        hv[i] = slow ? __hip_atomic_load(sp[i], __ATOMIC_RELAXED,
                                                         __HIP_MEMORY_SCOPE_AGENT)
                                     : *(volatile const ull_t*)fp[i];
            }
#pragma unroll
            for (int i = 0; i < 8; ++i) {
                int c = tid + 256 * i;
                int row = c >> 7, c4 = (c & 127) * 4;
                *(ull_t*)(hlds + row * 520 + c4) =
                    hv[i] - 0x0001000100010001ULL;   // decode bf16+1
            }
        }
        if (tid < 128) {
            int row = tid >> 3, c8 = (tid & 7) * 8;
            *(v8s*)(inplds + row * 136 + 64 + c8) = mreg;
            *(v8s*)(d1b + row * 72 + c8) = dreg;
        }
        __syncthreads();

        // ---- SA: xh + 2 gate chains share A-frags; gamma; xc epilogue ----
        v4f accx = {0.f, 0.f, 0.f, 0.f};
        v4f accg0 = {0.f, 0.f, 0.f, 0.f}, accg1 = {0.f, 0.f, 0.f, 0.f};
#pragma unroll
        for (int kt = 0; kt < 16; ++kt) {
            v8s a = *(const v8s*)(hlds + l15 * 520 + kt * 32 + quad * 8);
            accx = __builtin_amdgcn_mfma_f32_16x16x32_bf16(a, whisF[kt], accx, 0, 0, 0);
            accg0 = __builtin_amdgcn_mfma_f32_16x16x32_bf16(a, whhF[0][kt], accg0, 0, 0, 0);
            accg1 = __builtin_amdgcn_mfma_f32_16x16x32_bf16(a, whhF[1][kt], accg1, 0, 0, 0);
        }
        if (w < 2) {
            v4f acc = {0.f, 0.f, 0.f, 0.f};
#pragma unroll
            for (int kt = 0; kt < 2; ++kt) {
                v8s a = *(const v8s*)(d1b + l15 * 72 + kt * 32 + quad * 8);
                acc = __builtin_amdgcn_mfma_f32_16x16x32_bf16(a, wghF[kt], acc, 0, 0, 0);
            }
#pragma unroll
            for (int r = 0; r < 4; ++r) {
                float s = acc[r] + bghv;
                gam[(quad * 4 + r) * 36 + w * 16 + l15] = (s > 0.f) ? __expf(-s) : 1.f;
            }
        }
        float xh4[4];
#pragma unroll
        for (int r = 0; r < 4; ++r) {
            float xh = accx[r] + bhistv;
            float xc = m4r[r] * v4r[r] + (1.f - m4r[r]) * xh;
            xclds[(quad * 4 + r) * 72 + colC] = f2b(xc);
            xh4[r] = xh;
        }
        __syncthreads();

        // ---- SC: z_h MFMA; c_h/c_c epilogue; out store ----
        {
            v4f accz = {0.f, 0.f, 0.f, 0.f};
#pragma unroll
            for (int kt = 0; kt < 2; ++kt) {
                v8s a = *(const v8s*)(xclds + l15 * 72 + kt * 32 + quad * 8);
                accz = __builtin_amdgcn_mfma_f32_16x16x32_bf16(a, wfF[kt], accz, 0, 0, 0);
            }
#pragma unroll
            for (int r = 0; r < 4; ++r) {
                float zh = accz[r] + bfeatv;
                float ch = a4r[r] * zh + (1.f - a4r[r]) * xh4[r];
                float cc = m4r[r] * v4r[r] + (1.f - m4r[r]) * ch;
                int row = quad * 4 + r;
                inplds[row * 136 + colC] = f2b(cc);
                if (cb == 0)
                    out[(size_t)(b0 + row) * 16384 + t * 64 + colC] = cc;
            }
        }
        __syncthreads();

        // ---- SE: gates Wih part; gate planes ----
#pragma unroll
        for (int nt2 = 0; nt2 < 2; ++nt2) {
            v4f acc = (nt2 == 0) ? accg0 : accg1;
#pragma unroll
            for (int kt = 0; kt < 4; ++kt) {
                v8s a = *(const v8s*)(inplds + l15 * 136 + kt * 32 + quad * 8);
                acc = __builtin_amdgcn_mfma_f32_16x16x32_bf16(a, wihF[nt2][kt], acc, 0, 0, 0);
            }
#pragma unroll
            for (int r = 0; r < 4; ++r)
                gl[w * 576 + (quad * 4 + r) * 36 + nt2 * 16 + l15] = acc[r] + biasv[nt2];
        }
        __syncthreads();

        // ---- SF: LSTM + decay + dual h store; dual pre-zero slot t+4 ----
        if (tid < 128) {
            ull_t outv = 0;
#pragma unroll
            for (int j = 0; j < 4; ++j) {
                int hcl = sf_c4 + j;
                float gi = gl[0 * 576 + sf_row * 36 + hcl];
                float gf = gl[1 * 576 + sf_row * 36 + hcl];
                float gg = gl[2 * 576 + sf_row * 36 + hcl];
                float go = gl[3 * 576 + sf_row * 36 + hcl];
                float si = 1.f / (1.f + __expf(-gi));
                float sf = 1.f / (1.f + __expf(-gf));
                float tg = 1.f - 2.f / (__expf(2.f * gg) + 1.f);
                float so = 1.f / (1.f + __expf(-go));
                float cn = sf * c_reg4[j] + si * tg;
                c_reg4[j] = cn;
                float hn = so * (1.f - 2.f / (__expf(2.f * cn) + 1.f));
                float g = gam[sf_row * 36 + hcl];
                outv |= (ull_t)(ushort_t)(f2b(hn * g) + 1) << (16 * j);
            }
            size_t myoff = (size_t)(b0 + sf_row) * 512 + cb * 32 + sf_c4;
            if (t < 255) {
                size_t so_ = (size_t)((t + 1) & 7) * 131072 + myoff;
                *(volatile ull_t*)(hfast + so_) = outv;
                __hip_atomic_store((ull_t*)(hslow + so_), outv,
                                   __ATOMIC_RELAXED, __HIP_MEMORY_SCOPE_AGENT);
            }
            if (t + 4 < 256) {
                size_t zo = (size_t)((t + 4) & 7) * 131072 + myoff;
                *(volatile ull_t*)(hfast + zo) = 0ULL;
                __hip_atomic_store((ull_t*)(hslow + zo), 0ULL,
                                   __ATOMIC_RELAXED, __HIP_MEMORY_SCOPE_AGENT);
            }
        }
        __syncthreads();   // drains vmcnt: LDS reuse + publishes stores
    }
}

extern "C" void kernel_launch(void* const* d_in, const int* in_sizes, int n_in,
                              void* d_out, int out_size, void* d_ws, size_t ws_size,
                              hipStream_t stream) {
    const float* data  = (const float*)d_in[0];
    const float* Wih   = (const float*)d_in[1];
    const float* Whh   = (const float*)d_in[2];
    const float* bih   = (const float*)d_in[3];
    const float* bhh   = (const float*)d_in[4];
    const float* Wgh   = (const float*)d_in[5];
    const float* bgh   = (const float*)d_in[6];
    const float* Wgx   = (const float*)d_in[7];
    const float* bgx   = (const float*)d_in[8];
    const float* Whist = (const float*)d_in[9];
    const float* bhist = (const float*)d_in[10];
    const float* Wfeat = (const float*)d_in[11];
    const float* bfeat = (const float*)d_in[12];
    const float* Wcomb = (const float*)d_in[13];
    const float* bcomb = (const float*)d_in[14];
    float* out = (float*)d_out;

    char* ws = (char*)d_ws;
    const size_t NTBC = 256UL * 256 * 64;
    ushort_t* valuesb = (ushort_t*)ws; ws += NTBC * 2;
    ushort_t* masksp  = (ushort_t*)ws; ws += NTBC * 2;
    ushort_t* deltasp = (ushort_t*)ws; ws += NTBC * 2;
    ushort_t* gammax  = (ushort_t*)ws; ws += NTBC * 2;
    ushort_t* alphap  = (ushort_t*)ws; ws += NTBC * 2;
    ushort_t* Wih_b   = (ushort_t*)ws; ws += 2048UL * 128 * 2;
    ushort_t* Whh_b   = (ushort_t*)ws; ws += 2048UL * 512 * 2;
    ushort_t* Wgh_b   = (ushort_t*)ws; ws += 512UL * 64 * 2;
    ushort_t* Whist_b = (ushort_t*)ws; ws += 64UL * 512 * 2;
    ushort_t* Wfeat_b = (ushort_t*)ws; ws += 64UL * 64 * 2;
    ushort_t* hfast   = (ushort_t*)ws; ws += 8UL * 131072 * 2;  // 2 MB fast ring
    ushort_t* hslow   = (ushort_t*)ws; ws += 8UL * 131072 * 2;  // 2 MB slow ring
    // total ~46.6 MiB

    k_setup<<<5520, 256, 0, stream>>>(Wih, Whh, Wgh, Whist, Wfeat,
                                      Wih_b, Whh_b, Wgh_b, Whist_b, Wfeat_b,
                                      (ull_t*)hfast);   // zeros hfast+hslow (contiguous)
    k_pre<<<512, 256, 0, stream>>>(data, Wgx, bgx, valuesb, masksp, deltasp, gammax);
    k_alpha<<<4096, 256, 0, stream>>>(gammax, masksp, Wcomb, bcomb, alphap);
    k_run<<<256, 256, 0, stream>>>(valuesb, masksp, deltasp, alphap,
                                   Wih_b, Whh_b, bih, bhh,
                                   Wgh_b, bgh, Whist_b, bhist,
                                   Wfeat_b, bfeat, hfast, hslow, out);
}

// Round 11
// 1177.235 us; speedup vs baseline: 1.5244x; 1.2740x over previous
//
#include <hip/hip_runtime.h>

typedef unsigned short ushort_t;
typedef unsigned int uint_t;
typedef unsigned long long ull_t;
typedef short v8s __attribute__((ext_vector_type(8)));
typedef float v4f __attribute__((ext_vector_type(4)));

__device__ __forceinline__ float b2f(ushort_t u) {
    uint_t x = ((uint_t)u) << 16;
    float f;
    __builtin_memcpy(&f, &x, 4);
    return f;
}
__device__ __forceinline__ ushort_t f2b(float f) {
    uint_t x;
    __builtin_memcpy(&x, &f, 4);
    uint_t r = (x + 0x7FFFu + ((x >> 16) & 1u)) >> 16;
    return (ushort_t)r;
}

// ---------------------------------------------------------------------------
// k_setup: zero 8-slot h ring (64 blocks) + weight fp32->bf16 conversions.
// grid = 64 + 1024 + 4096 + 128 + 128 + 16 = 5456 blocks of 256.
// ---------------------------------------------------------------------------
__global__ __launch_bounds__(256) void k_setup(
    const float* __restrict__ Wih, const float* __restrict__ Whh,
    const float* __restrict__ Wgh, const float* __restrict__ Whist,
    const float* __restrict__ Wfeat,
    ushort_t* __restrict__ Wih_b, ushort_t* __restrict__ Whh_b,
    ushort_t* __restrict__ Wgh_b, ushort_t* __restrict__ Whist_b,
    ushort_t* __restrict__ Wfeat_b, ull_t* __restrict__ hbufs) {
    int bid = blockIdx.x, tid = threadIdx.x;
    if (bid < 64) {   // zero 8 slots x 131072 u16 = 262144 ull
        ull_t* p = hbufs + (size_t)bid * 4096 + tid;
#pragma unroll
        for (int i = 0; i < 16; ++i) p[i * 256] = 0;
        return;
    }
    bid -= 64;
    const float* src; ushort_t* dst; int n;
    if (bid < 1024)      { src = Wih;   dst = Wih_b;   n = 262144; }
    else if (bid < 5120) { bid -= 1024; src = Whh;   dst = Whh_b;   n = 1048576; }
    else if (bid < 5248) { bid -= 5120; src = Wgh;   dst = Wgh_b;   n = 32768; }
    else if (bid < 5376) { bid -= 5248; src = Whist; dst = Whist_b; n = 32768; }
    else                 { bid -= 5376; src = Wfeat; dst = Wfeat_b; n = 4096; }
    int i = bid * 256 + tid;
    if (i < n) dst[i] = f2b(src[i]);
}

// ---------------------------------------------------------------------------
// k_pre: 512 blocks; each block = 32 (b,c) pairs x 8 threads over T chunks.
// ---------------------------------------------------------------------------
__global__ __launch_bounds__(256) void k_pre(
    const float* __restrict__ data, const float* __restrict__ Wgx,
    const float* __restrict__ bgx,
    ushort_t* __restrict__ values, ushort_t* __restrict__ masks,
    ushort_t* __restrict__ deltas, ushort_t* __restrict__ gammax) {
    __shared__ int lastl[32][9];
    int tid = threadIdx.x;
    int j = tid >> 5, p = tid & 31;
    int pid = blockIdx.x * 32 + p;      // 0..16383
    int b = pid >> 6, c = pid & 63;
    float wd = Wgx[c * 64 + c], bg = bgx[c];
    int t0 = j * 32;
    const float* dp = data + (size_t)b * 16384 + c;
    float v[32]; uint_t bits = 0;
#pragma unroll
    for (int s = 0; s < 32; ++s) {
        float x = dp[(t0 + s) * 64];
        bool obs = (x == x);
        v[s] = obs ? x : 0.f;
        bits |= obs ? (1u << s) : 0u;
    }
    uint_t vb = bits;
    if (j == 0) vb &= ~1u;              // t=0 never counts as observation
    int lastloc = 0;
    if (vb) lastloc = t0 + (31 - __clz(vb));
    lastl[p][j] = lastloc;
    __syncthreads();
    int L = 0;
    for (int jj = 0; jj < j; ++jj) L = max(L, lastl[p][jj]);
#pragma unroll
    for (int s = 0; s < 32; ++s) {
        int t = t0 + s;
        float m = ((bits >> s) & 1) ? 1.f : 0.f;
        float d = (t == 0) ? 0.f : (float)(t - L);
        float sg = d * wd + bg;
        float gx = (sg > 0.f) ? __expf(-sg) : 1.f;
        size_t o = (size_t)t * 16384 + pid;
        values[o] = f2b(v[s]); masks[o] = f2b(m);
        deltas[o] = f2b(d);    gammax[o] = f2b(gx);
        if (((bits >> s) & 1) && t >= 1) L = t;
    }
}

// ---------------------------------------------------------------------------
// k_alpha: 4096 blocks x 16 (t,b) rows (T*B = 65536 rows).
// ---------------------------------------------------------------------------
__global__ __launch_bounds__(256) void k_alpha(
    const ushort_t* __restrict__ gammax, const ushort_t* __restrict__ masks,
    const float* __restrict__ Wcomb, const float* __restrict__ bcomb,
    ushort_t* __restrict__ alpha) {
    __shared__ __attribute__((aligned(16))) ushort_t wl[64 * 136];
    __shared__ __attribute__((aligned(16))) ushort_t al[16 * 136];
    int tid = threadIdx.x;
    for (int idx = tid; idx < 8192; idx += 256) {
        int r = idx >> 7, kcol = idx & 127;
        wl[r * 136 + kcol] = f2b(Wcomb[idx]);
    }
    int tb0 = blockIdx.x * 16;
    for (int idx = tid; idx < 2048; idx += 256) {
        int r = idx >> 7, kcol = idx & 127;
        al[r * 136 + kcol] = (kcol < 64)
            ? gammax[(size_t)(tb0 + r) * 64 + kcol]
            : masks[(size_t)(tb0 + r) * 64 + (kcol - 64)];
    }
    __syncthreads();
    int i = tid & 63, rg = (tid >> 6) * 4;
    float bc = bcomb[i];
    float acc[4] = {bc, bc, bc, bc};
#pragma unroll
    for (int k8 = 0; k8 < 16; ++k8) {
        v8s w8 = *(const v8s*)(wl + i * 136 + k8 * 8);
#pragma unroll
        for (int rr = 0; rr < 4; ++rr) {
            v8s a8 = *(const v8s*)(al + (rg + rr) * 136 + k8 * 8);
#pragma unroll
            for (int q = 0; q < 8; ++q)
                acc[rr] += b2f((ushort_t)a8[q]) * b2f((ushort_t)w8[q]);
        }
    }
#pragma unroll
    for (int rr = 0; rr < 4; ++rr)
        alpha[(size_t)(tb0 + rg + rr) * 64 + i] = f2b(acc[rr]);
}

// ---------------------------------------------------------------------------
// k_run: R8 exchange (8-slot ring, relaxed agent atomics, bf16+1 data-poll),
// restructured step:
//  - pre-zero of slot (t+4)%8 moved to pre-poll region (off the SF tail)
//  - SA = x_h only (2x8 split chains) + gamma -> x_c available ASAP
//  - SB = z_h(2) -> 8 gates_hh -> c_c epilogue + balanced out store -> 24 more
//  - out store balanced across the group: wg cb stores row cb (256B each)
// ---------------------------------------------------------------------------
__global__ __launch_bounds__(256, 1) void k_run(
    const ushort_t* __restrict__ values, const ushort_t* __restrict__ masks,
    const ushort_t* __restrict__ deltas, const ushort_t* __restrict__ alpha,
    const ushort_t* __restrict__ Wih, const ushort_t* __restrict__ Whh,
    const float* __restrict__ bih, const float* __restrict__ bhh,
    const ushort_t* __restrict__ Wgh, const float* __restrict__ bgh,
    const ushort_t* __restrict__ Whist, const float* __restrict__ bhist,
    const ushort_t* __restrict__ Wfeat, const float* __restrict__ bfeat,
    ushort_t* __restrict__ hbufs, float* __restrict__ out) {
    __shared__ __attribute__((aligned(16))) ushort_t hlds[16 * 520];
    __shared__ __attribute__((aligned(16))) ushort_t inplds[16 * 136];
    __shared__ __attribute__((aligned(16))) ushort_t xclds[16 * 72];
    __shared__ __attribute__((aligned(16))) ushort_t d1b[16 * 72];
    __shared__ __attribute__((aligned(16))) float gl[4 * 16 * 36];
    __shared__ __attribute__((aligned(16))) float gam[16 * 36];

    int tid = threadIdx.x;
    int w = tid >> 6;
    int lane = tid & 63;
    int l15 = lane & 15, quad = lane >> 4;
    int wg = blockIdx.x;
    int rb = wg & 15, cb = wg >> 4;
    int b0 = rb * 16;

    // ---- persistent weight fragments ----
    v8s whhF[2][16], wihF[2][4], whisF[16], wfF[2], wghF[2] = {};
    float biasv[2];
#pragma unroll
    for (int nt2 = 0; nt2 < 2; ++nt2) {
        int hc = cb * 32 + nt2 * 16 + l15;
        int rW = w * 512 + hc;
        const ushort_t* whrow = Whh + (size_t)rW * 512;
        const ushort_t* wirow = Wih + (size_t)rW * 128;
#pragma unroll
        for (int kt = 0; kt < 16; ++kt)
            whhF[nt2][kt] = *(const v8s*)(whrow + kt * 32 + quad * 8);
#pragma unroll
        for (int kt = 0; kt < 4; ++kt)
            wihF[nt2][kt] = *(const v8s*)(wirow + kt * 32 + quad * 8);
        biasv[nt2] = bih[rW] + bhh[rW];
    }
    int colC = w * 16 + l15;
    {
        const ushort_t* hrow = Whist + (size_t)colC * 512;
#pragma unroll
        for (int kt = 0; kt < 16; ++kt)
            whisF[kt] = *(const v8s*)(hrow + kt * 32 + quad * 8);
        const ushort_t* frow = Wfeat + colC * 64;
#pragma unroll
        for (int kt = 0; kt < 2; ++kt) {
            int k0 = kt * 32 + quad * 8;
            v8s bb = *(const v8s*)(frow + k0);
#pragma unroll
            for (int j = 0; j < 8; ++j)
                if (k0 + j == colC) bb[j] = 0;   // zero diagonal
            wfF[kt] = bb;
        }
    }
    float bghv = 0.f;
    if (w < 2) {
        int gcol = cb * 32 + w * 16 + l15;
        const ushort_t* grow = Wgh + gcol * 64;
#pragma unroll
        for (int kt = 0; kt < 2; ++kt)
            wghF[kt] = *(const v8s*)(grow + kt * 32 + quad * 8);
        bghv = bgh[gcol];
    }
    float bhistv = bhist[colC];
    float bfeatv = bfeat[colC];

    int sf_row = tid >> 3, sf_c4 = (tid & 7) * 4;
    size_t myoff = (size_t)(b0 + sf_row) * 512 + cb * 32 + sf_c4;
    float c_reg4[4] = {0.f, 0.f, 0.f, 0.f};

    for (int t = 0; t < 256; ++t) {
        // ---- P: prefetch + early pre-zero of slot (t+4)%8 ----
        float v4r[4], m4r[4], a4r[4];
#pragma unroll
        for (int r = 0; r < 4; ++r) {
            int row = quad * 4 + r;
            size_t g = (size_t)t * 16384 + (b0 + row) * 64 + colC;
            v4r[r] = b2f(values[g]);
            m4r[r] = b2f(masks[g]);
            a4r[r] = b2f(alpha[g]);
        }
        v8s mreg = {}, dreg = {};
        if (tid < 128) {
            int row = tid >> 3, c8 = (tid & 7) * 8;
            int tn = (t < 255) ? t + 1 : 255;
            mreg = *(const v8s*)(masks + (size_t)t * 16384 + (b0 + row) * 64 + c8);
            dreg = *(const v8s*)(deltas + (size_t)tn * 16384 + (b0 + row) * 64 + c8);
            if (t + 4 < 256) {
                size_t zo = (size_t)((t + 4) & 7) * 131072 + myoff;
                __hip_atomic_store((ull_t*)(hbufs + zo), 0ULL,
                                   __ATOMIC_RELAXED, __HIP_MEMORY_SCOPE_AGENT);
            }
        }

        // ---- S0: poll h(t) data; decode; stage LDS ----
        if (t == 0) {
            v8s z = {0, 0, 0, 0, 0, 0, 0, 0};
            for (int idx = tid; idx < 1040; idx += 256) ((v8s*)hlds)[idx] = z;
        } else {
            const ushort_t* hb = hbufs + (size_t)(t & 7) * 131072;
            const ull_t* hp[8];
            ull_t hv[8];
#pragma unroll
            for (int i = 0; i < 8; ++i) {
                int c = tid + 256 * i;
                int row = c >> 7, c4 = (c & 127) * 4;
                hp[i] = (const ull_t*)(hb + (size_t)(b0 + row) * 512 + c4);
                hv[i] = __hip_atomic_load(hp[i], __ATOMIC_RELAXED,
                                          __HIP_MEMORY_SCOPE_AGENT);
            }
            int guard = 0;
            while (true) {
                bool any = false;
#pragma unroll
                for (int i = 0; i < 8; ++i) any |= (hv[i] == 0);
                if (!any || ++guard > (1 << 20)) break;
                __builtin_amdgcn_s_sleep(1);
#pragma unroll
                for (int i = 0; i < 8; ++i)
                    if (hv[i] == 0)
                        hv[i] = __hip_atomic_load(hp[i], __ATOMIC_RELAXED,
                                                  __HIP_MEMORY_SCOPE_AGENT);
            }
#pragma unroll
            for (int i = 0; i < 8; ++i) {
                int c = tid + 256 * i;
                int row = c >> 7, c4 = (c & 127) * 4;
                *(ull_t*)(hlds + row * 520 + c4) =
                    hv[i] - 0x0001000100010001ULL;   // decode bf16+1
            }
        }
        if (tid < 128) {
            int row = tid >> 3, c8 = (tid & 7) * 8;
            *(v8s*)(inplds + row * 136 + 64 + c8) = mreg;
            *(v8s*)(d1b + row * 72 + c8) = dreg;
        }
        __syncthreads();

        // ---- SA: x_h only (2x8 split chains) + gamma; x_c epilogue ----
        {
            v4f ax0 = {0.f, 0.f, 0.f, 0.f}, ax1 = {0.f, 0.f, 0.f, 0.f};
#pragma unroll
            for (int kt = 0; kt < 8; ++kt) {
                v8s a0 = *(const v8s*)(hlds + l15 * 520 + kt * 32 + quad * 8);
                v8s a1 = *(const v8s*)(hlds + l15 * 520 + (kt + 8) * 32 + quad * 8);
                ax0 = __builtin_amdgcn_mfma_f32_16x16x32_bf16(a0, whisF[kt], ax0, 0, 0, 0);
                ax1 = __builtin_amdgcn_mfma_f32_16x16x32_bf16(a1, whisF[kt + 8], ax1, 0, 0, 0);
            }
            if (w < 2) {
                v4f acc = {0.f, 0.f, 0.f, 0.f};
#pragma unroll
                for (int kt = 0; kt < 2; ++kt) {
                    v8s a = *(const v8s*)(d1b + l15 * 72 + kt * 32 + quad * 8);
                    acc = __builtin_amdgcn_mfma_f32_16x16x32_bf16(a, wghF[kt], acc, 0, 0, 0);
                }
#pragma unroll
                for (int r = 0; r < 4; ++r) {
                    float s = acc[r] + bghv;
                    gam[(quad * 4 + r) * 36 + w * 16 + l15] = (s > 0.f) ? __expf(-s) : 1.f;
                }
            }
#pragma unroll
            for (int r = 0; r < 4; ++r) {
                float xh = ax0[r] + ax1[r] + bhistv;
                float xc = m4r[r] * v4r[r] + (1.f - m4r[r]) * xh;
                xclds[(quad * 4 + r) * 72 + colC] = f2b(xc);
                v4r[r] = m4r[r] * v4r[r];   // reuse: m*v
                m4r[r] = xh;                 // reuse: x_h
            }
        }
        __syncthreads();

        // ---- SB: z_h(2) -> 8 gates_hh -> c_c epilogue + out -> 24 gates ----
        v4f accg0 = {0.f, 0.f, 0.f, 0.f}, accg1 = {0.f, 0.f, 0.f, 0.f};
        {
            v4f accz = {0.f, 0.f, 0.f, 0.f};
#pragma unroll
            for (int kt = 0; kt < 2; ++kt) {
                v8s a = *(const v8s*)(xclds + l15 * 72 + kt * 32 + quad * 8);
                accz = __builtin_amdgcn_mfma_f32_16x16x32_bf16(a, wfF[kt], accz, 0, 0, 0);
            }
#pragma unroll
            for (int kt = 0; kt < 4; ++kt) {
                v8s a = *(const v8s*)(hlds + l15 * 520 + kt * 32 + quad * 8);
                accg0 = __builtin_amdgcn_mfma_f32_16x16x32_bf16(a, whhF[0][kt], accg0, 0, 0, 0);
                accg1 = __builtin_amdgcn_mfma_f32_16x16x32_bf16(a, whhF[1][kt], accg1, 0, 0, 0);
            }
#pragma unroll
            for (int r = 0; r < 4; ++r) {
                // v4r = m*v, m4r = x_h (repurposed in SA)
                float zh = accz[r] + bfeatv;
                float ch = a4r[r] * zh + (1.f - a4r[r]) * m4r[r];
                float cc = v4r[r] + ch - (v4r[r] != 0.f ? ch : 0.f) * 0.f; // placeholder avoided
                cc = v4r[r] + (1.f - (v4r[r] == v4r[r] ? 0.f : 0.f)) * 0.f; // (unused)
                // correct: cc = m*v + (1-m)*ch ; recover (1-m) from stored x_h? m was
                // overwritten -- recompute via v4r: m*v known; need m.  Use alpha trick:
                cc = 0.f;
                (void)cc;
                // NOTE: we keep m in inplds (cols 64..127) -- read it back cheaply:
                float m = b2f(inplds[(quad * 4 + r) * 136 + 64 + colC]);
                float ccv = m * 0.f + v4r[r] + (1.f - m) * ch;
                int row = quad * 4 + r;
                inplds[row * 136 + colC] = f2b(ccv);
                if (row == cb)
                    out[(size_t)(b0 + row) * 16384 + t * 64 + colC] = ccv;
            }
#pragma unroll
            for (int kt = 4; kt < 16; ++kt) {
                v8s a = *(const v8s*)(hlds + l15 * 520 + kt * 32 + quad * 8);
                accg0 = __builtin_amdgcn_mfma_f32_16x16x32_bf16(a, whhF[0][kt], accg0, 0, 0, 0);
                accg1 = __builtin_amdgcn_mfma_f32_16x16x32_bf16(a, whhF[1][kt], accg1, 0, 0, 0);
            }
        }
        __syncthreads();

        // ---- SE: gates Wih part; gate planes ----
#pragma unroll
        for (int nt2 = 0; nt2 < 2; ++nt2) {
            v4f acc = (nt2 == 0) ? accg0 : accg1;
#pragma unroll
            for (int kt = 0; kt < 4; ++kt) {
                v8s a = *(const v8s*)(inplds + l15 * 136 + kt * 32 + quad * 8);
                acc = __builtin_amdgcn_mfma_f32_16x16x32_bf16(a, wihF[nt2][kt], acc, 0, 0, 0);
            }
#pragma unroll
            for (int r = 0; r < 4; ++r)
                gl[w * 576 + (quad * 4 + r) * 36 + nt2 * 16 + l15] = acc[r] + biasv[nt2];
        }
        __syncthreads();

        // ---- SF: LSTM + decay + h store ----
        if (tid < 128) {
            ull_t outv = 0;
#pragma unroll
            for (int j = 0; j < 4; ++j) {
                int hcl = sf_c4 + j;
                float gi = gl[0 * 576 + sf_row * 36 + hcl];
                float gf = gl[1 * 576 + sf_row * 36 + hcl];
                float gg = gl[2 * 576 + sf_row * 36 + hcl];
                float go = gl[3 * 576 + sf_row * 36 + hcl];
                float si = 1.f / (1.f + __expf(-gi));
                float sf = 1.f / (1.f + __expf(-gf));
                float tg = 1.f - 2.f / (__expf(2.f * gg) + 1.f);
                float so = 1.f / (1.f + __expf(-go));
                float cn = sf * c_reg4[j] + si * tg;
                c_reg4[j] = cn;
                float hn = so * (1.f - 2.f / (__expf(2.f * cn) + 1.f));
                float g = gam[sf_row * 36 + hcl];
                outv |= (ull_t)(ushort_t)(f2b(hn * g) + 1) << (16 * j);
            }
            if (t < 255) {
                size_t so_ = (size_t)((t + 1) & 7) * 131072 + myoff;
                __hip_atomic_store((ull_t*)(hbufs + so_), outv,
                                   __ATOMIC_RELAXED, __HIP_MEMORY_SCOPE_AGENT);
            }
        }
        __syncthreads();   // drains vmcnt: LDS reuse + publishes stores
    }
}

extern "C" void kernel_launch(void* const* d_in, const int* in_sizes, int n_in,
                              void* d_out, int out_size, void* d_ws, size_t ws_size,
                              hipStream_t stream) {
    const float* data  = (const float*)d_in[0];
    const float* Wih   = (const float*)d_in[1];
    const float* Whh   = (const float*)d_in[2];
    const float* bih   = (const float*)d_in[3];
    const float* bhh   = (const float*)d_in[4];
    const float* Wgh   = (const float*)d_in[5];
    const float* bgh   = (const float*)d_in[6];
    const float* Wgx   = (const float*)d_in[7];
    const float* bgx   = (const float*)d_in[8];
    const float* Whist = (const float*)d_in[9];
    const float* bhist = (const float*)d_in[10];
    const float* Wfeat = (const float*)d_in[11];
    const float* bfeat = (const float*)d_in[12];
    const float* Wcomb = (const float*)d_in[13];
    const float* bcomb = (const float*)d_in[14];
    float* out = (float*)d_out;

    char* ws = (char*)d_ws;
    const size_t NTBC = 256UL * 256 * 64;
    ushort_t* valuesb = (ushort_t*)ws; ws += NTBC * 2;
    ushort_t* masksp  = (ushort_t*)ws; ws += NTBC * 2;
    ushort_t* deltasp = (ushort_t*)ws; ws += NTBC * 2;
    ushort_t* gammax  = (ushort_t*)ws; ws += NTBC * 2;
    ushort_t* alphap  = (ushort_t*)ws; ws += NTBC * 2;
    ushort_t* Wih_b   = (ushort_t*)ws; ws += 2048UL * 128 * 2;
    ushort_t* Whh_b   = (ushort_t*)ws; ws += 2048UL * 512 * 2;
    ushort_t* Wgh_b   = (ushort_t*)ws; ws += 512UL * 64 * 2;
    ushort_t* Whist_b = (ushort_t*)ws; ws += 64UL * 512 * 2;
    ushort_t* Wfeat_b = (ushort_t*)ws; ws += 64UL * 64 * 2;
    ushort_t* hbufs   = (ushort_t*)ws; ws += 8UL * 131072 * 2;  // 2 MB ring
    // total ~44.6 MiB

    k_setup<<<5456, 256, 0, stream>>>(Wih, Whh, Wgh, Whist, Wfeat,
                                      Wih_b, Whh_b, Wgh_b, Whist_b, Wfeat_b,
                                      (ull_t*)hbufs);
    k_pre<<<512, 256, 0, stream>>>(data, Wgx, bgx, valuesb, masksp, deltasp, gammax);
    k_alpha<<<4096, 256, 0, stream>>>(gammax, masksp, Wcomb, bcomb, alphap);
    k_run<<<256, 256, 0, stream>>>(valuesb, masksp, deltasp, alphap,
                                   Wih_b, Whh_b, bih, bhh,
                                   Wgh_b, bgh, Whist_b, bhist,
                                   Wfeat_b, bfeat, hbufs, out);
}